// Round 8
// baseline (411.475 us; speedup 1.0000x reference)
//
#include <hip/hip_runtime.h>

// Problem constants (fixed by setup_inputs)
#define BB 4
#define CC 64      // feature channels
#define KK 16      // neighbors
#define NN 16384   // points
#define NTB 256    // points per window = 4 pairs x 64 points, 8 waves
#define NWIN 2     // n-windows per block (diagnostic round: grid halved)

typedef __attribute__((ext_vector_type(8))) short short8;     // 8 bf16 (MFMA A/B)
typedef __attribute__((ext_vector_type(4))) float floatx4;    // MFMA C/D
typedef __attribute__((ext_vector_type(2))) _Float16 half2v;  // packed f16 pair

__device__ __forceinline__ unsigned short f2bf_rtne(float x) {  // RTNE f32->bf16
    unsigned u = __builtin_bit_cast(unsigned, x);
    u += 0x7FFFu + ((u >> 16) & 1u);
    return (unsigned short)(u >> 16);
}

// pack two f32 into bf16x2 (round-half-up via +0x8000, then v_perm byte-select)
__device__ __forceinline__ unsigned pack_bf16x2(float lo, float hi) {
    unsigned a = __builtin_bit_cast(unsigned, lo) + 0x8000u;
    unsigned b = __builtin_bit_cast(unsigned, hi) + 0x8000u;
    return __builtin_amdgcn_perm(b, a, 0x07060302u);  // {b.hi16, a.hi16}
}

// cvt_pkrtz: two f32 -> packed f16 pair (low = first arg)
__device__ __forceinline__ half2v cvt2h(float a, float b) {
    return __builtin_bit_cast(half2v, __builtin_amdgcn_cvt_pkrtz(a, b));
}
__device__ __forceinline__ unsigned pk2u(float a, float b) {
    return __builtin_bit_cast(unsigned, __builtin_amdgcn_cvt_pkrtz(a, b));
}

#if __has_builtin(__builtin_amdgcn_fdot2)
#define DOT2(a, b, c) __builtin_amdgcn_fdot2((a), (b), (c), false)
#else
__device__ __forceinline__ float dot2_fb(half2v a, half2v b, float c) {
    return fmaf((float)a[0], (float)b[0], fmaf((float)a[1], (float)b[1], c));
}
#define DOT2(a, b, c) dot2_fb((a), (b), (c))
#endif

// ---------------------------------------------------------------------------
// One-time: repack lin_w (f32 [64][1024]) into bf16 MFMA B-fragments in the
// exact per-wave load order: [chunk ci][kk][nt][lane]{8 bf16}. 128 KB, L2-hot.
// Also zeroes the BN partial-sum buffer (fused_main accumulates via atomics).
// ---------------------------------------------------------------------------
__global__ __launch_bounds__(256)
void prep_bfrag(const float* __restrict__ lin_w, unsigned short* __restrict__ bfrag,
                float* __restrict__ part)
{
    const int tid  = blockIdx.x * 256 + threadIdx.x;  // 0..8191
    if (tid < 512) part[tid] = 0.0f;                  // BN sum/sumsq partials

    const int lane = tid & 63;
    const int g    = tid >> 6;            // 0..127 = (ci,kk,nt)
    const int ci   = g >> 4;
    const int kk   = (g >> 2) & 3;
    const int nt   = g & 3;
    const int r    = lane & 15;
    const int sq   = lane >> 4;

    const float* src = lin_w + (size_t)(nt * 16 + r) * 1024 + ci * 128 + kk * 32 + sq * 8;
    unsigned short v[8];
    #pragma unroll
    for (int j = 0; j < 8; ++j) v[j] = f2bf_rtne(src[j]);
    *(uint4*)(bfrag + ((size_t)g * 64 + lane) * 8) = *(const uint4*)v;
}

// ---------------------------------------------------------------------------
// Fused weightnet + aggregation + linear(MFMA) + BN partial reduction.
//
// ROUND-8 DIAGNOSTIC: grid 128, each block processes NWIN=2 n-windows
// (window bid and bid+128) sequentially; everything inside the window loop
// is R7-verbatim (verified 397.4, absmax 0.03125). Purpose: make fused_main
// exceed the ~160 us rocprof top-5 cutoff (1-GiB workspace poisons) IF it is
// per-CU-bound, yielding first-ever PMC for the hot kernel. Discriminates:
//   per-CU-bound   -> dispatch ~240-280 us, visible w/ counters, total ~530
//   device-BW-bound-> dispatch ~120-140 us, invisible,          total ~397
// A trailing __syncthreads() per window protects s_p/sb LDS reuse across
// windows. BN atomics accumulate across both windows (part zeroed by prep).
// lin_b dropped: training-mode BN cancels per-channel shifts.
// ---------------------------------------------------------------------------
__global__ __launch_bounds__(512, 2)
void fused_main(const float* __restrict__ points,
                const float* __restrict__ coordinate,
                const float* __restrict__ w1,
                const float* __restrict__ b1,
                const unsigned short* __restrict__ bfrag,
                float* __restrict__ y_out,    // [B][C][N] pre-BN
                float* __restrict__ part)     // [2][B][64] sums / sumsq
{
    __shared__ unsigned int s_p[2][2][8][256];  // 32 KB [buf][ch][kp][n]
    __shared__ uint4 s_a[4][2][1024];           // 128 KB [pair][buf][Mt*256+kk*64+r*4+sq]

    const int t    = threadIdx.x;
    const int lane = t & 63;
    const int wv   = __builtin_amdgcn_readfirstlane(t >> 6);  // 0..7
    const int P    = wv >> 1;      // pair id 0..3
    const int h    = wv & 1;       // o-half within pair
    const int r    = lane & 15;
    const int sq   = lane >> 4;

    for (int win = 0; win < NWIN; ++win) {
        const int wid = blockIdx.x + win * 128;   // global window 0..255
        const int b   = wid >> 6;                 // 64 windows per batch
        const int n0b = (wid & 63) * NTB;         // window's point base
        const int n0p = n0b + P * 64;             // pair's point base

        // ---- weightnet into f16-pair registers: wh[j][kp], o = 8h + j
        half2v wh[8][8];
        {
            const float* coordB = coordinate + (size_t)b * 3 * KK * NN + n0p + lane;
            float c0[KK], c1[KK], c2[KK];
            #pragma unroll
            for (int k = 0; k < KK; ++k) {
                c0[k] = coordB[(0 * KK + k) * NN];
                c1[k] = coordB[(1 * KK + k) * NN];
                c2[k] = coordB[(2 * KK + k) * NN];
            }
            #pragma unroll
            for (int j = 0; j < 8; ++j) {
                const int o = 8 * h + j;
                const float w1x = w1[o * 3 + 0];
                const float w1y = w1[o * 3 + 1];
                const float w1z = w1[o * 3 + 2];
                const float bo  = b1[o];
                #pragma unroll
                for (int kp = 0; kp < 8; ++kp) {
                    float v0 = fmaf(w1x, c0[2 * kp],     fmaf(w1y, c1[2 * kp],     fmaf(w1z, c2[2 * kp],     bo)));
                    float v1 = fmaf(w1x, c0[2 * kp + 1], fmaf(w1y, c1[2 * kp + 1], fmaf(w1z, c2[2 * kp + 1], bo)));
                    wh[j][kp] = cvt2h(fmaxf(v0, 0.0f), fmaxf(v1, 0.0f));
                }
            }
        }

        floatx4 acc[2][4];
        #pragma unroll
        for (int m = 0; m < 2; ++m)
            #pragma unroll
            for (int nt = 0; nt < 4; ++nt) acc[m][nt] = (floatx4){0.f, 0.f, 0.f, 0.f};

        // staging base: lane covers n = n0b + 4*lane .. +3 of each (c,k) row
        const float* pS = points + (size_t)b * CC * KK * NN + n0b + 4 * lane;

        float4 stF[4][2][2];  // [slot][ch][row] in-flight granule loads (4-deep)

#define ISSUE(SLOT, G) {                                                        \
        const int cA = 2 * (G);                                                 \
        stF[SLOT][0][0] = *(const float4*)(pS + (size_t)(cA * 16 + 2 * wv) * NN);       \
        stF[SLOT][0][1] = *(const float4*)(pS + (size_t)(cA * 16 + 2 * wv + 1) * NN);   \
        stF[SLOT][1][0] = *(const float4*)(pS + (size_t)((cA + 1) * 16 + 2 * wv) * NN); \
        stF[SLOT][1][1] = *(const float4*)(pS + (size_t)((cA + 1) * 16 + 2 * wv + 1) * NN); }

#define WRITE(SLOT, BUF) {                                                      \
        _Pragma("unroll")                                                       \
        for (int ch = 0; ch < 2; ++ch) {                                        \
            const float4 A = stF[SLOT][ch][0], Bv = stF[SLOT][ch][1];           \
            uint4 W;                                                            \
            W.x = pk2u(A.x, Bv.x);  W.y = pk2u(A.y, Bv.y);                      \
            W.z = pk2u(A.z, Bv.z);  W.w = pk2u(A.w, Bv.w);                      \
            *(uint4*)&s_p[BUF][ch][wv][4 * lane] = W;                           \
        } }

#define CONSUME(GEXPR, BUF, GG) {                                               \
        const int g_ = (GEXPR);                                                 \
        _Pragma("unroll")                                                       \
        for (int chh = 0; chh < 2; ++chh) {                                     \
            const int cl = (2 * (GG) + chh) & 7;                                \
            half2v ph[8];                                                       \
            _Pragma("unroll")                                                   \
            for (int kp = 0; kp < 8; ++kp)                                      \
                ph[kp] = __builtin_bit_cast(half2v, s_p[BUF][chh][kp][P * 64 + lane]); \
            float a8[8];                                                        \
            _Pragma("unroll")                                                   \
            for (int j = 0; j < 8; ++j) {                                       \
                float a = 0.f;                                                  \
                _Pragma("unroll")                                               \
                for (int kp = 0; kp < 8; ++kp) a = DOT2(ph[kp], wh[j][kp], a);  \
                a8[j] = a;                                                      \
            }                                                                   \
            uint4 pk;                                                           \
            pk.x = pack_bf16x2(a8[0], a8[1]);                                   \
            pk.y = pack_bf16x2(a8[2], a8[3]);                                   \
            pk.z = pack_bf16x2(a8[4], a8[5]);                                   \
            pk.w = pack_bf16x2(a8[6], a8[7]);                                   \
            s_a[P][((2 * g_ + chh) >> 3) & 1]                                   \
               [(lane >> 4) * 256 + (cl >> 1) * 64 + (lane & 15) * 4            \
                + (cl & 1) * 2 + h] = pk;                                       \
        } }

        // ---- prologue: prime 4 granules, write granule 0, barrier
        ISSUE(0, 0)
        ISSUE(1, 1)
        ISSUE(2, 2)
        ISSUE(3, 3)
        WRITE(0, 0)
        asm volatile("s_waitcnt lgkmcnt(0)\n\ts_barrier" ::: "memory");

        for (int ci = 0; ci < 8; ++ci) {
            #pragma unroll
            for (int gg = 0; gg < 4; ++gg) {
                const int g = ci * 4 + gg;
                if (g + 4 < 32) ISSUE(g & 3, g + 4)
                CONSUME(g, g & 1, gg)
                if (g + 1 < 32) WRITE((g + 1) & 3, (g + 1) & 1)

                if (gg == 3) {
                    uint4 bf_c[4];
                    #pragma unroll
                    for (int nt = 0; nt < 4; ++nt)
                        bf_c[nt] = *(const uint4*)(bfrag + ((((size_t)ci * 4 + 0) * 4 + nt) * 64 + lane) * 8);

                    asm volatile("s_waitcnt lgkmcnt(0)\n\ts_barrier" ::: "memory");

                    const uint4* saR = &s_a[P][ci & 1][0];
                    #pragma unroll
                    for (int kk = 0; kk < 4; ++kk) {
                        uint4 bf_n[4];
                        if (kk < 3) {
                            #pragma unroll
                            for (int nt = 0; nt < 4; ++nt)
                                bf_n[nt] = *(const uint4*)(bfrag + ((((size_t)ci * 4 + kk + 1) * 4 + nt) * 64 + lane) * 8);
                        }
                        short8 af[2];
                        #pragma unroll
                        for (int m = 0; m < 2; ++m)
                            af[m] = __builtin_bit_cast(short8, saR[(2 * h + m) * 256 + kk * 64 + r * 4 + sq]);
                        #pragma unroll
                        for (int m = 0; m < 2; ++m)
                            #pragma unroll
                            for (int nt = 0; nt < 4; ++nt)
                                acc[m][nt] = __builtin_amdgcn_mfma_f32_16x16x32_bf16(
                                    af[m], __builtin_bit_cast(short8, bf_c[nt]), acc[m][nt], 0, 0, 0);
                        #pragma unroll
                        for (int nt = 0; nt < 4; ++nt) bf_c[nt] = bf_n[nt];
                    }
                } else {
                    asm volatile("s_waitcnt lgkmcnt(0)\n\ts_barrier" ::: "memory");
                }
            }
        }
#undef ISSUE
#undef WRITE
#undef CONSUME

        // ---- epilogue: store y + BN partial sums (scratch reuses s_p[0]).
        float* yB  = y_out + (size_t)b * CC * NN + n0p;
        float* sb  = (float*)&s_p[0][0][0][0];   // [16 row-tiles][64 oc] sums
        float* sb2 = sb + 1024;                  // [16][64] sumsq
        #pragma unroll
        for (int m = 0; m < 2; ++m)
            #pragma unroll
            for (int nt = 0; nt < 4; ++nt) {
                const int oc = nt * 16 + r;
                const floatx4 v = acc[m][nt];
                *(float4*)(yB + (size_t)oc * NN + (2 * h + m) * 16 + sq * 4) =
                    make_float4(v[0], v[1], v[2], v[3]);

                float s  = v[0] + v[1] + v[2] + v[3];
                float ss = v[0] * v[0] + v[1] * v[1] + v[2] * v[2] + v[3] * v[3];
                s  += __shfl_xor(s, 16);  s  += __shfl_xor(s, 32);
                ss += __shfl_xor(ss, 16); ss += __shfl_xor(ss, 32);
                if (lane < 16) {                 // lane == r, sq == 0
                    sb [(wv * 2 + m) * 64 + oc] = s;
                    sb2[(wv * 2 + m) * 64 + oc] = ss;
                }
            }
        __syncthreads();
        if (t < 64) {   // one wave: 64 oc, stride-1 LDS reads, 2 atomics/lane
            float S = 0.f, SS = 0.f;
            #pragma unroll
            for (int q = 0; q < 16; ++q) {
                S  += sb [q * 64 + t];
                SS += sb2[q * 64 + t];
            }
            atomicAdd(&part[b * 64 + t], S);
            atomicAdd(&part[256 + b * 64 + t], SS);
        }
        __syncthreads();   // protect s_p/sb reuse by next window's staging
    }
}

// ---------------------------------------------------------------------------
// BN stats + apply in ONE kernel: each block redundantly computes the
// 64-channel (a,b) from part[] (512 L2-hot floats).
// ---------------------------------------------------------------------------
__global__ __launch_bounds__(256)
void bn_apply(float* __restrict__ y, const float* __restrict__ part,
              const float* __restrict__ gamma, const float* __restrict__ beta)
{
    __shared__ float sab[2 * CC];
    if (threadIdx.x < CC) {
        const int ch = threadIdx.x;
        float S = 0.f, SS = 0.f;
        #pragma unroll
        for (int bb = 0; bb < BB; ++bb) {
            S  += part[bb * 64 + ch];
            SS += part[256 + bb * 64 + ch];
        }
        const float inv  = 1.0f / (float)(BB * NN);
        const float mean = S * inv;
        const float var  = SS * inv - mean * mean;
        const float a    = gamma[ch] * rsqrtf(var + 1e-5f);
        sab[ch]      = a;
        sab[CC + ch] = beta[ch] - mean * a;
    }
    __syncthreads();

    const size_t i = (size_t)blockIdx.x * 256 + threadIdx.x;  // float4 index
    float4* p = (float4*)y;
    float4 v = p[i];
    const int ch = (int)((i * 4) >> 14) & 63;  // (elem / N) % C
    const float a = sab[ch], bb = sab[CC + ch];
    v.x = fmaxf(fmaf(a, v.x, bb), 0.0f);
    v.y = fmaxf(fmaf(a, v.y, bb), 0.0f);
    v.z = fmaxf(fmaf(a, v.z, bb), 0.0f);
    v.w = fmaxf(fmaf(a, v.w, bb), 0.0f);
    p[i] = v;
}

extern "C" void kernel_launch(void* const* d_in, const int* in_sizes, int n_in,
                              void* d_out, int out_size, void* d_ws, size_t ws_size,
                              hipStream_t stream)
{
    const float* xyz        = (const float*)d_in[0];
    const float* points     = (const float*)d_in[1];
    const float* coordinate = (const float*)d_in[2];
    const float* w1         = (const float*)d_in[3];
    const float* b1         = (const float*)d_in[4];
    const float* lin_w      = (const float*)d_in[5];
    // d_in[6] = lin_b: unused — training-mode BN cancels per-channel shifts
    const float* gamma      = (const float*)d_in[7];
    const float* beta       = (const float*)d_in[8];

    float* out = (float*)d_out;

    // workspace: [0,128K) bfrag bf16; then 512 floats partials
    unsigned short* bfrag = (unsigned short*)d_ws;
    float* part = (float*)d_ws + 32768;

    const size_t xyz_elems = (size_t)BB * NN * 3;  // output 0 passthrough
    (void)hipMemcpyAsync(out, xyz, xyz_elems * sizeof(float),
                         hipMemcpyDeviceToDevice, stream);

    float* y_out = out + xyz_elems;  // [B][C][N]

    prep_bfrag<<<32, 256, 0, stream>>>(lin_w, bfrag, part);
    fused_main<<<BB * (NN / NTB) / NWIN, 512, 0, stream>>>(
        points, coordinate, w1, b1, bfrag, y_out, part);
    bn_apply<<<(BB * CC * NN) / 4 / 256, 256, 0, stream>>>(y_out, part, gamma, beta);
}

// Round 10
// 394.908 us; speedup vs baseline: 1.0420x; 1.0420x over previous
//
#include <hip/hip_runtime.h>

// Problem constants (fixed by setup_inputs)
#define BB 4
#define CC 64      // feature channels
#define KK 16      // neighbors
#define NN 16384   // points
#define NTB 256    // points per block = 4 pairs x 64 points, 8 waves

typedef __attribute__((ext_vector_type(8))) short short8;     // 8 bf16 (MFMA A/B)
typedef __attribute__((ext_vector_type(4))) float floatx4;    // MFMA C/D
typedef __attribute__((ext_vector_type(2))) _Float16 half2v;  // packed f16 pair

__device__ __forceinline__ unsigned short f2bf_rtne(float x) {  // RTNE f32->bf16
    unsigned u = __builtin_bit_cast(unsigned, x);
    u += 0x7FFFu + ((u >> 16) & 1u);
    return (unsigned short)(u >> 16);
}

// pack two f32 into bf16x2 (round-half-up via +0x8000, then v_perm byte-select)
__device__ __forceinline__ unsigned pack_bf16x2(float lo, float hi) {
    unsigned a = __builtin_bit_cast(unsigned, lo) + 0x8000u;
    unsigned b = __builtin_bit_cast(unsigned, hi) + 0x8000u;
    return __builtin_amdgcn_perm(b, a, 0x07060302u);  // {b.hi16, a.hi16}
}

// cvt_pkrtz: two f32 -> packed f16 pair (low = first arg)
__device__ __forceinline__ half2v cvt2h(float a, float b) {
    return __builtin_bit_cast(half2v, __builtin_amdgcn_cvt_pkrtz(a, b));
}
__device__ __forceinline__ unsigned pk2u(float a, float b) {
    return __builtin_bit_cast(unsigned, __builtin_amdgcn_cvt_pkrtz(a, b));
}

#if __has_builtin(__builtin_amdgcn_fdot2)
#define DOT2(a, b, c) __builtin_amdgcn_fdot2((a), (b), (c), false)
#else
__device__ __forceinline__ float dot2_fb(half2v a, half2v b, float c) {
    return fmaf((float)a[0], (float)b[0], fmaf((float)a[1], (float)b[1], c));
}
#define DOT2(a, b, c) dot2_fb((a), (b), (c))
#endif

// ---------------------------------------------------------------------------
// One-time: repack lin_w (f32 [64][1024]) into bf16 MFMA B-fragments in the
// exact per-wave load order: [chunk ci][kk][nt][lane]{8 bf16}. 128 KB, L2-hot.
// Also zeroes the BN partial-sum buffer (fused_main accumulates via atomics).
// ---------------------------------------------------------------------------
__global__ __launch_bounds__(256)
void prep_bfrag(const float* __restrict__ lin_w, unsigned short* __restrict__ bfrag,
                float* __restrict__ part)
{
    const int tid  = blockIdx.x * 256 + threadIdx.x;  // 0..8191
    if (tid < 512) part[tid] = 0.0f;                  // BN sum/sumsq partials

    const int lane = tid & 63;
    const int g    = tid >> 6;            // 0..127 = (ci,kk,nt)
    const int ci   = g >> 4;
    const int kk   = (g >> 2) & 3;
    const int nt   = g & 3;
    const int r    = lane & 15;
    const int sq   = lane >> 4;

    const float* src = lin_w + (size_t)(nt * 16 + r) * 1024 + ci * 128 + kk * 32 + sq * 8;
    unsigned short v[8];
    #pragma unroll
    for (int j = 0; j < 8; ++j) v[j] = f2bf_rtne(src[j]);
    *(uint4*)(bfrag + ((size_t)g * 64 + lane) * 8) = *(const uint4*)v;
}

// ---------------------------------------------------------------------------
// Fused weightnet + aggregation + linear(MFMA) + BN partial reduction.
//
// SESSION-BEST STRUCTURE (verified 396.5 us total, absmax 0.03125):
// block = 512 thr = 8 waves = 4 independent pairs over a 256-point window.
// Per-wave compute (wh, dot2, pack, s_a layout, MFMA, bf double-buffer) is
// the R3-verified math; points delivery is block-cooperative LDS staging:
//   - wave wv stages k-rows {2wv, 2wv+1} of each channel as lane-contiguous
//     float4: ONE global_load_dwordx4 = 1 KB contiguous of one (c,k) row;
//     pair redundancy eliminated.
//   - T14 split staging: issue loads 2 granules ahead into registers,
//     convert (cvt_pkrtz) + ds_write AFTER the intervening consume.
//   - granule = 2 channels, s_p double-buffered (32 KB); consume reads the
//     pair's 64-column slice: bank-free 2-way.
// LDS = 32 KB s_p + 128 KB s_a = 160 KB exactly -> 1 block/CU, 8 waves.
// One lgkm-only barrier per granule (vmcnt never drained).
// lin_b dropped: training-mode BN cancels per-channel shifts.
//
// Session ledger (why this is final): consumer reorder (R1 null), occupancy
// restructure (R2 -77%), float2 chunking (R4 -8%), staging depth 4 (R7 null),
// per-CU doubling discriminator (R8: device-pattern-bound confirmed), BN
// grid-sync fusion (R5 silent no-op under graph capture; R9 container kill).
// fused_main is pinned by its 1KB-piece/64KB-stride DRAM pattern.
// ---------------------------------------------------------------------------
__global__ __launch_bounds__(512, 2)
void fused_main(const float* __restrict__ points,
                const float* __restrict__ coordinate,
                const float* __restrict__ w1,
                const float* __restrict__ b1,
                const unsigned short* __restrict__ bfrag,
                float* __restrict__ y_out,    // [B][C][N] pre-BN
                float* __restrict__ part)     // [2][B][64] sums / sumsq
{
    __shared__ unsigned int s_p[2][2][8][256];  // 32 KB [buf][ch][kp][n]
    __shared__ uint4 s_a[4][2][1024];           // 128 KB [pair][buf][Mt*256+kk*64+r*4+sq]

    const int t    = threadIdx.x;
    const int lane = t & 63;
    const int wv   = __builtin_amdgcn_readfirstlane(t >> 6);  // 0..7
    const int P    = wv >> 1;      // pair id 0..3
    const int h    = wv & 1;       // o-half within pair
    const int r    = lane & 15;
    const int sq   = lane >> 4;

    const int bid = blockIdx.x;
    const int b   = bid >> 6;            // 64 blocks per batch
    const int n0b = (bid & 63) * NTB;    // block's point base
    const int n0p = n0b + P * 64;        // pair's point base

    // ---- weightnet into f16-pair registers: wh[j][kp], o = 8h + j
    half2v wh[8][8];
    {
        const float* coordB = coordinate + (size_t)b * 3 * KK * NN + n0p + lane;
        float c0[KK], c1[KK], c2[KK];
        #pragma unroll
        for (int k = 0; k < KK; ++k) {
            c0[k] = coordB[(0 * KK + k) * NN];
            c1[k] = coordB[(1 * KK + k) * NN];
            c2[k] = coordB[(2 * KK + k) * NN];
        }
        #pragma unroll
        for (int j = 0; j < 8; ++j) {
            const int o = 8 * h + j;
            const float w1x = w1[o * 3 + 0];
            const float w1y = w1[o * 3 + 1];
            const float w1z = w1[o * 3 + 2];
            const float bo  = b1[o];
            #pragma unroll
            for (int kp = 0; kp < 8; ++kp) {
                float v0 = fmaf(w1x, c0[2 * kp],     fmaf(w1y, c1[2 * kp],     fmaf(w1z, c2[2 * kp],     bo)));
                float v1 = fmaf(w1x, c0[2 * kp + 1], fmaf(w1y, c1[2 * kp + 1], fmaf(w1z, c2[2 * kp + 1], bo)));
                wh[j][kp] = cvt2h(fmaxf(v0, 0.0f), fmaxf(v1, 0.0f));
            }
        }
    }

    floatx4 acc[2][4];
    #pragma unroll
    for (int m = 0; m < 2; ++m)
        #pragma unroll
        for (int nt = 0; nt < 4; ++nt) acc[m][nt] = (floatx4){0.f, 0.f, 0.f, 0.f};

    // staging base: lane covers n = n0b + 4*lane .. +3 of each (c,k) row
    const float* pS = points + (size_t)b * CC * KK * NN + n0b + 4 * lane;

    float4 stF[2][2][2];  // [slot][ch][row] in-flight granule loads

    // issue granule G's 4 rows (2 ch x k={2wv,2wv+1}) into stF[SLOT]
#define ISSUE(SLOT, G) {                                                        \
        const int cA = 2 * (G);                                                 \
        stF[SLOT][0][0] = *(const float4*)(pS + (size_t)(cA * 16 + 2 * wv) * NN);       \
        stF[SLOT][0][1] = *(const float4*)(pS + (size_t)(cA * 16 + 2 * wv + 1) * NN);   \
        stF[SLOT][1][0] = *(const float4*)(pS + (size_t)((cA + 1) * 16 + 2 * wv) * NN); \
        stF[SLOT][1][1] = *(const float4*)(pS + (size_t)((cA + 1) * 16 + 2 * wv + 1) * NN); }

    // convert + ds_write granule from stF[SLOT] into s_p[BUF]
#define WRITE(SLOT, BUF) {                                                      \
        _Pragma("unroll")                                                       \
        for (int ch = 0; ch < 2; ++ch) {                                        \
            const float4 A = stF[SLOT][ch][0], Bv = stF[SLOT][ch][1];           \
            uint4 W;                                                            \
            W.x = pk2u(A.x, Bv.x);  W.y = pk2u(A.y, Bv.y);                      \
            W.z = pk2u(A.z, Bv.z);  W.w = pk2u(A.w, Bv.w);                      \
            *(uint4*)&s_p[BUF][ch][wv][4 * lane] = W;                           \
        } }

    // consume granule (2 channels): dot2 + pack + s_a store (R3-verbatim math)
#define CONSUME(GEXPR, BUF, GG) {                                               \
        const int g_ = (GEXPR);                                                 \
        _Pragma("unroll")                                                       \
        for (int chh = 0; chh < 2; ++chh) {                                     \
            const int cl = (2 * (GG) + chh) & 7;   /* compile-time after unroll */ \
            half2v ph[8];                                                       \
            _Pragma("unroll")                                                   \
            for (int kp = 0; kp < 8; ++kp)                                      \
                ph[kp] = __builtin_bit_cast(half2v, s_p[BUF][chh][kp][P * 64 + lane]); \
            float a8[8];                                                        \
            _Pragma("unroll")                                                   \
            for (int j = 0; j < 8; ++j) {                                       \
                float a = 0.f;                                                  \
                _Pragma("unroll")                                               \
                for (int kp = 0; kp < 8; ++kp) a = DOT2(ph[kp], wh[j][kp], a);  \
                a8[j] = a;                                                      \
            }                                                                   \
            uint4 pk;                                                           \
            pk.x = pack_bf16x2(a8[0], a8[1]);                                   \
            pk.y = pack_bf16x2(a8[2], a8[3]);                                   \
            pk.z = pack_bf16x2(a8[4], a8[5]);                                   \
            pk.w = pack_bf16x2(a8[6], a8[7]);                                   \
            s_a[P][((2 * g_ + chh) >> 3) & 1]                                   \
               [(lane >> 4) * 256 + (cl >> 1) * 64 + (lane & 15) * 4            \
                + (cl & 1) * 2 + h] = pk;                                       \
        } }

    // ---- prologue: prime 2 granules, write granule 0, barrier
    ISSUE(0, 0)
    ISSUE(1, 1)
    WRITE(0, 0)
    asm volatile("s_waitcnt lgkmcnt(0)\n\ts_barrier" ::: "memory");

    for (int ci = 0; ci < 8; ++ci) {
        #pragma unroll
        for (int gg = 0; gg < 4; ++gg) {
            const int g = ci * 4 + gg;
            if (g + 2 < 32) ISSUE(gg & 1, g + 2)      // into freed slot
            CONSUME(g, gg & 1, gg)
            if (g + 1 < 32) WRITE((gg + 1) & 1, (gg + 1) & 1)

            if (gg == 3) {
                // region ci complete: B-frags kk=0 pre-barrier, then MFMA
                uint4 bf_c[4];
                #pragma unroll
                for (int nt = 0; nt < 4; ++nt)
                    bf_c[nt] = *(const uint4*)(bfrag + ((((size_t)ci * 4 + 0) * 4 + nt) * 64 + lane) * 8);

                asm volatile("s_waitcnt lgkmcnt(0)\n\ts_barrier" ::: "memory");

                const uint4* saR = &s_a[P][ci & 1][0];
                #pragma unroll
                for (int kk = 0; kk < 4; ++kk) {
                    uint4 bf_n[4];
                    if (kk < 3) {
                        #pragma unroll
                        for (int nt = 0; nt < 4; ++nt)
                            bf_n[nt] = *(const uint4*)(bfrag + ((((size_t)ci * 4 + kk + 1) * 4 + nt) * 64 + lane) * 8);
                    }
                    short8 af[2];
                    #pragma unroll
                    for (int m = 0; m < 2; ++m)
                        af[m] = __builtin_bit_cast(short8, saR[(2 * h + m) * 256 + kk * 64 + r * 4 + sq]);
                    #pragma unroll
                    for (int m = 0; m < 2; ++m)
                        #pragma unroll
                        for (int nt = 0; nt < 4; ++nt)
                            acc[m][nt] = __builtin_amdgcn_mfma_f32_16x16x32_bf16(
                                af[m], __builtin_bit_cast(short8, bf_c[nt]), acc[m][nt], 0, 0, 0);
                    #pragma unroll
                    for (int nt = 0; nt < 4; ++nt) bf_c[nt] = bf_n[nt];
                }
            } else {
                asm volatile("s_waitcnt lgkmcnt(0)\n\ts_barrier" ::: "memory");
            }
        }
    }
#undef ISSUE
#undef WRITE
#undef CONSUME

    // ---- epilogue: store y + BN partial sums.
    // D col=lane&15 (oc), row=quad*4+reg; pair's Mt index = 2h+m.
    // BN scratch reuses s_p[0] (last consumed at g=30, barrier'd at gg=2).
    float* yB  = y_out + (size_t)b * CC * NN + n0p;
    float* sb  = (float*)&s_p[0][0][0][0];   // [16 row-tiles][64 oc] sums
    float* sb2 = sb + 1024;                  // [16][64] sumsq
    #pragma unroll
    for (int m = 0; m < 2; ++m)
        #pragma unroll
        for (int nt = 0; nt < 4; ++nt) {
            const int oc = nt * 16 + r;
            const floatx4 v = acc[m][nt];
            *(float4*)(yB + (size_t)oc * NN + (2 * h + m) * 16 + sq * 4) =
                make_float4(v[0], v[1], v[2], v[3]);

            float s  = v[0] + v[1] + v[2] + v[3];
            float ss = v[0] * v[0] + v[1] * v[1] + v[2] * v[2] + v[3] * v[3];
            s  += __shfl_xor(s, 16);  s  += __shfl_xor(s, 32);
            ss += __shfl_xor(ss, 16); ss += __shfl_xor(ss, 32);
            if (lane < 16) {                 // lane == r, sq == 0
                sb [(wv * 2 + m) * 64 + oc] = s;
                sb2[(wv * 2 + m) * 64 + oc] = ss;
            }
        }
    __syncthreads();
    if (t < 64) {   // one wave: 64 oc, stride-1 LDS reads, 2 atomics/lane
        float S = 0.f, SS = 0.f;
        #pragma unroll
        for (int q = 0; q < 16; ++q) {
            S  += sb [q * 64 + t];
            SS += sb2[q * 64 + t];
        }
        atomicAdd(&part[b * 64 + t], S);
        atomicAdd(&part[256 + b * 64 + t], SS);
    }
}

__global__ void bn_stats(const float* __restrict__ part,
                         const float* __restrict__ gamma,
                         const float* __restrict__ beta,
                         float* __restrict__ ab)
{
    const int ch = threadIdx.x;
    float S = 0.f, SS = 0.f;
    #pragma unroll
    for (int b = 0; b < BB; ++b) {
        S  += part[b * 64 + ch];
        SS += part[256 + b * 64 + ch];
    }
    const float inv  = 1.0f / (float)(BB * NN);
    const float mean = S * inv;
    const float var  = SS * inv - mean * mean;
    const float a    = gamma[ch] * rsqrtf(var + 1e-5f);
    ab[ch]      = a;
    ab[CC + ch] = beta[ch] - mean * a;
}

__global__ __launch_bounds__(256)
void bn_apply(float* __restrict__ y, const float* __restrict__ ab)
{
    const size_t i = (size_t)blockIdx.x * 256 + threadIdx.x;  // float4 index
    float4* p = (float4*)y;
    float4 v = p[i];
    const int ch = (int)((i * 4) >> 14) & 63;  // (elem / N) % C
    const float a = ab[ch], bb = ab[CC + ch];
    v.x = fmaxf(fmaf(a, v.x, bb), 0.0f);
    v.y = fmaxf(fmaf(a, v.y, bb), 0.0f);
    v.z = fmaxf(fmaf(a, v.z, bb), 0.0f);
    v.w = fmaxf(fmaf(a, v.w, bb), 0.0f);
    p[i] = v;
}

extern "C" void kernel_launch(void* const* d_in, const int* in_sizes, int n_in,
                              void* d_out, int out_size, void* d_ws, size_t ws_size,
                              hipStream_t stream)
{
    const float* xyz        = (const float*)d_in[0];
    const float* points     = (const float*)d_in[1];
    const float* coordinate = (const float*)d_in[2];
    const float* w1         = (const float*)d_in[3];
    const float* b1         = (const float*)d_in[4];
    const float* lin_w      = (const float*)d_in[5];
    // d_in[6] = lin_b: unused — training-mode BN cancels per-channel shifts
    const float* gamma      = (const float*)d_in[7];
    const float* beta       = (const float*)d_in[8];

    float* out = (float*)d_out;

    // workspace: [0,128K) bfrag bf16; then 512 floats partials; then 128 ab
    unsigned short* bfrag = (unsigned short*)d_ws;
    float* part = (float*)d_ws + 32768;
    float* ab   = part + 512;

    const size_t xyz_elems = (size_t)BB * NN * 3;  // output 0 passthrough
    (void)hipMemcpyAsync(out, xyz, xyz_elems * sizeof(float),
                         hipMemcpyDeviceToDevice, stream);

    float* y_out = out + xyz_elems;  // [B][C][N]

    prep_bfrag<<<32, 256, 0, stream>>>(lin_w, bfrag, part);
    fused_main<<<BB * (NN / NTB), 512, 0, stream>>>(
        points, coordinate, w1, b1, bfrag, y_out, part);
    bn_stats<<<1, 64, 0, stream>>>(part, gamma, beta, ab);
    bn_apply<<<(BB * CC * NN) / 4 / 256, 256, 0, stream>>>(y_out, ab);
}